// Round 7
// baseline (394.527 us; speedup 1.0000x reference)
//
#include <hip/hip_runtime.h>
#include <stdint.h>

typedef unsigned short u16;
typedef unsigned int u32;
typedef unsigned long long u64;
typedef __attribute__((ext_vector_type(8))) short short8;
typedef __attribute__((ext_vector_type(4))) float floatx4;

#define DIM 128
#define DIM2 64     // h dwords per row (2 bf16 per dword)
#define NBK 1024    // scatter scan width >= B = ceil(N/128) = 782
#define NB_SH 7     // 128 nodes per bucket
#define AGG_NB 128
#define AGG_CAP 4608  // max staged records/bucket (mean 4096, std 64 -> +8 sigma)
#define SC_C 8192     // edges per scatter chunk / region size
#define NSEG 512      // segment-directory capacity >= nsc = 391

__device__ __forceinline__ u32 f32_to_bf16_rne(float f) {
  u32 u = __float_as_uint(f);
  u32 r = u + 0x7fffu + ((u >> 16) & 1u);
  return r >> 16;
}
__device__ __forceinline__ float bf16_to_f32(u32 u) { return __uint_as_float(u << 16); }
__device__ __forceinline__ u32 pack2bf16(float a, float b) {
  return f32_to_bf16_rne(a) | (f32_to_bf16_rne(b) << 16);
}

union FragU {
  u32 d[4];
  short8 s;
};

// h = x @ W^T via bf16 MFMA. Grid-stride over 64-node tiles with exactly 256
// WGs (1/CU); W staged once per CU.
__global__ __launch_bounds__(256) void gemm_mfma(const float* __restrict__ x,
                                                 const float* __restrict__ W,
                                                 u16* __restrict__ h, int N) {
  __shared__ u32 Wl[DIM * DIM2];  // 32 KB
  int tid = threadIdx.x;
#pragma unroll
  for (int i = 0; i < 8; ++i) {
    int ga = tid + 256 * i;
    int o = ga >> 4, g = ga & 15;
    const float* src = W + (size_t)o * DIM + g * 8;
    floatx4 f0 = *(const floatx4*)src;
    floatx4 f1 = *(const floatx4*)(src + 4);
    int slot = (g + o) & 15;
    u32* dst = &Wl[o * DIM2 + slot * 4];
    dst[0] = pack2bf16(f0.x, f0.y);
    dst[1] = pack2bf16(f0.z, f0.w);
    dst[2] = pack2bf16(f1.x, f1.y);
    dst[3] = pack2bf16(f1.z, f1.w);
  }
  __syncthreads();

  int lane = tid & 63;
  int wave = tid >> 6;
  int m = lane & 15;
  int kg = lane >> 4;
  int ntile = (N + 63) >> 6;  // 64-node tiles

  for (int t = blockIdx.x; t < ntile; t += 256) {
    int nodeBase = t * 64 + wave * 16;
    if (nodeBase >= N) continue;

    short8 a[4];
    const float* xr = x + (size_t)(nodeBase + m) * DIM + kg * 8;
#pragma unroll
    for (int kt = 0; kt < 4; ++kt) {
      floatx4 f0 = *(const floatx4*)(xr + kt * 32);
      floatx4 f1 = *(const floatx4*)(xr + kt * 32 + 4);
      FragU fu;
      fu.d[0] = pack2bf16(f0.x, f0.y);
      fu.d[1] = pack2bf16(f0.z, f0.w);
      fu.d[2] = pack2bf16(f1.x, f1.y);
      fu.d[3] = pack2bf16(f1.z, f1.w);
      a[kt] = fu.s;
    }

#pragma unroll
    for (int ot = 0; ot < 8; ++ot) {
      int o = ot * 16 + m;
      floatx4 acc = {0.f, 0.f, 0.f, 0.f};
#pragma unroll
      for (int kt = 0; kt < 4; ++kt) {
        int slot = (kt * 4 + kg + o) & 15;
        short8 b = *(short8*)&Wl[o * DIM2 + slot * 4];
        acc = __builtin_amdgcn_mfma_f32_16x16x32_bf16(a[kt], b, acc, 0, 0, 0);
      }
#pragma unroll
      for (int r = 0; r < 4; ++r) {
        int node = nodeBase + kg * 4 + r;
        h[(size_t)node * DIM + ot * 16 + m] = (u16)f32_to_bf16_rne(acc[r]);
      }
    }
  }
}

// Exclusive scan over NBK=1024 LDS counters, 4 contiguous per thread.
__device__ __forceinline__ void scan1024(u32* cnt, u32* excl, u32* wtot) {
  int tid = threadIdx.x, lane = tid & 63, wave = tid >> 6;
  u32 c[4], sum = 0;
#pragma unroll
  for (int k = 0; k < 4; ++k) {
    c[k] = cnt[tid * 4 + k];
    sum += c[k];
  }
  u32 inc = sum;
#pragma unroll
  for (int d = 1; d < 64; d <<= 1) {
    u32 t = __shfl_up(inc, d, 64);
    if (lane >= d) inc += t;
  }
  if (lane == 63) wtot[wave] = inc;
  __syncthreads();
  u32 wbase = 0;
  for (int w = 0; w < wave; ++w) wbase += wtot[w];
  u32 run = wbase + inc - sum;
#pragma unroll
  for (int k = 0; k < 4; ++k) {
    excl[tid * 4 + k] = run;
    run += c[k];
  }
  __syncthreads();
}

// Region-local sort-scatter (no global atomics). Each WG bucket-sorts its
// 8192-edge chunk in LDS, streams it to its OWN region (coalesced), and
// writes a TRANSPOSED directory dirT[b][wg] = (start<<16)|cnt so agg's
// per-bucket directory read is coalesced (R6's dir[wg][b] column read was
// 391 strided lines per WG).
__global__ __launch_bounds__(256) void sort_scatter(const int* __restrict__ rows,
                                                    const int* __restrict__ cols,
                                                    const float* __restrict__ vals,
                                                    u32* __restrict__ bcol,
                                                    u16* __restrict__ bval,
                                                    u32* __restrict__ dirT, int E, int B,
                                                    int nsc) {
  __shared__ u32 hist[NBK];    // counts -> running ptr
  __shared__ u32 starts[NBK];  // exclusive scan
  __shared__ u32 wtot[4];
  __shared__ u32 s_lo[SC_C];   // 32 KB
  __shared__ u16 s_val[SC_C];  // 16 KB
  int tid = threadIdx.x;
  int wg = blockIdx.x;
  int base = wg * SC_C;
  int tot = min(SC_C, E - base);

  for (int b = tid; b < NBK; b += 256) hist[b] = 0;
  __syncthreads();
  // pass 1: local bucket histogram
  for (int j = tid; j < tot; j += 256) {
    atomicAdd(&hist[((u32)rows[base + j]) >> NB_SH], 1u);
  }
  __syncthreads();
  scan1024(hist, starts, wtot);
  for (int b = tid; b < NBK; b += 256) hist[b] = starts[b];  // running ptrs
  __syncthreads();
  // pass 2: rank final records into bucket-grouped LDS (all reads coalesced)
  for (int j = tid; j < tot; j += 256) {
    u32 r = (u32)rows[base + j];
    u32 bk = r >> NB_SH;
    u32 p = atomicAdd(&hist[bk], 1u);
    s_lo[p] = ((r & 127u) << 25) | ((u32)cols[base + j] << 8);
    s_val[p] = (u16)f32_to_bf16_rne(vals[base + j]);
  }
  __syncthreads();
  // flush: pure streaming writes to own region
  for (int i = tid; i < tot; i += 256) {
    bcol[(size_t)base + i] = s_lo[i];
    bval[(size_t)base + i] = s_val[i];
  }
  // transposed directory (strided u32 writes, 1.2 MB total, L2-merged)
  for (int b = tid; b < B; b += 256) {
    dirT[(size_t)b * nsc + wg] = (starts[b] << 16) | (hist[b] - starts[b]);
  }
}

// One WG per 128-node bucket. Directory column read coalesced (dirT), segment
// scan, binary-search staging (segments now ~10.5 records -> halved read
// amplification), node counting-sort in LDS, flat walk with depth-8 gather
// pipeline, direct relu'd global flush.
__global__ __launch_bounds__(256) void agg_bucket(const u32* __restrict__ bcol,
                                                  const u16* __restrict__ bval,
                                                  const u32* __restrict__ dirT,
                                                  const u32* __restrict__ h,
                                                  float* __restrict__ out, int N,
                                                  int nsc, int B) {
  __shared__ u64 s_rec[AGG_CAP];  // 36 KB
  __shared__ u32 segdir[NSEG], segdst[NSEG];
  __shared__ u32 cnt[AGG_NB], excl[AGG_NB], ptr[AGG_NB], wtot[4];
  int tid = threadIdx.x, lane = tid & 63, wave = tid >> 6;
  int b = blockIdx.x;
  int nodeBase = b << NB_SH;
  int lane4 = lane * 4;
  const char* hb = (const char*)h;

  // coalesced directory row + zero node counters
  for (int w = tid; w < nsc; w += 256) segdir[w] = dirT[(size_t)b * nsc + w];
  if (tid < AGG_NB) cnt[tid] = 0;
  __syncthreads();
  // exclusive scan of segment counts (2 per thread, 512 logical)
  {
    int e0 = 2 * tid, e1 = e0 + 1;
    u32 c0 = (e0 < nsc) ? (segdir[e0] & 0xffffu) : 0u;
    u32 c1 = (e1 < nsc) ? (segdir[e1] & 0xffffu) : 0u;
    u32 s = c0 + c1, inc = s;
#pragma unroll
    for (int d = 1; d < 64; d <<= 1) {
      u32 t = __shfl_up(inc, d, 64);
      if (lane >= d) inc += t;
    }
    if (lane == 63) wtot[wave] = inc;
    __syncthreads();
    u32 wbase = 0;
    for (int w = 0; w < wave; ++w) wbase += wtot[w];
    u32 ex = wbase + inc - s;
    segdst[e0] = ex;
    segdst[e1] = ex + c0;
    __syncthreads();
  }
  int T = (int)(wtot[0] + wtot[1] + wtot[2] + wtot[3]);

  if (T <= AGG_CAP) {
    // pass A: stage records via segment search + node histogram
    u32 rlo[18], rv[18];
#pragma unroll
    for (int k = 0; k < 18; ++k) {
      int g = tid + 256 * k;
      rlo[k] = 0;
      rv[k] = 0;
      if (g < T) {
        int lo = 0, hi = nsc - 1;  // largest w with segdst[w] <= g
        while (lo < hi) {
          int mid = (lo + hi + 1) >> 1;
          if (segdst[mid] <= (u32)g) lo = mid; else hi = mid - 1;
        }
        u32 dv = segdir[lo];
        u32 src = (u32)lo * SC_C + (dv >> 16) + ((u32)g - segdst[lo]);
        rlo[k] = bcol[src];
        rv[k] = bval[src];
        atomicAdd(&cnt[rlo[k] >> 25], 1u);
      }
    }
    __syncthreads();
    // scan 128 node counters with one wave (2 per lane)
    if (tid < 64) {
      u32 c0 = cnt[2 * lane], c1 = cnt[2 * lane + 1];
      u32 s = c0 + c1, inc = s;
#pragma unroll
      for (int d = 1; d < 64; d <<= 1) {
        u32 t = __shfl_up(inc, d, 64);
        if (lane >= d) inc += t;
      }
      u32 ex = inc - s;
      excl[2 * lane] = ex;
      ptr[2 * lane] = ex;
      excl[2 * lane + 1] = ex + c0;
      ptr[2 * lane + 1] = ex + c0;
    }
    __syncthreads();
    // pass B: rank into node-sorted LDS staging (u64 records)
#pragma unroll
    for (int k = 0; k < 18; ++k) {
      int g = tid + 256 * k;
      if (g < T) {
        u32 p = atomicAdd(&ptr[rlo[k] >> 25], 1u);
        s_rec[p] = ((u64)(rv[k] << 16) << 32) | rlo[k];
      }
    }
    __syncthreads();
    // pass C: flat walk of my wave's 32 nodes' contiguous segment
    int wbeg = (int)excl[wave * 32];
    int wend = (int)ptr[wave * 32 + 31];
    float a0 = 0.f, a1 = 0.f;
    int curn = -1;
    for (int e = wbeg; e < wend; e += 8) {
      u32 lo8[8];
      float v8[8];
      u32 hd[8];
#pragma unroll
      for (int g = 0; g < 8; ++g) {
        int ee = e + g;
        bool act = ee < wend;
        u64 r = s_rec[act ? ee : (wend - 1)];  // wave-uniform broadcast read
        lo8[g] = (u32)r;
        v8[g] = act ? __uint_as_float((u32)(r >> 32)) : 0.f;
      }
#pragma unroll
      for (int g = 0; g < 8; ++g) {
        hd[g] = *(const u32*)(hb + ((lo8[g] & 0x01FFFF00u) + lane4));
      }
#pragma unroll
      for (int g = 0; g < 8; ++g) {
        int nid = __builtin_amdgcn_readfirstlane((int)(lo8[g] >> 25));
        if (nid != curn) {  // scalar branch, once per run (~32 records)
          if (curn >= 0) {
            float2 o = make_float2(fmaxf(a0, 0.f), fmaxf(a1, 0.f));
            *(float2*)(out + (size_t)(nodeBase + curn) * DIM + 2 * lane) = o;
          }
          curn = nid;
          a0 = 0.f;
          a1 = 0.f;
        }
        float v = v8[g];
        a0 += v * bf16_to_f32(hd[g] & 0xffffu);
        a1 += v * bf16_to_f32(hd[g] >> 16);
      }
    }
    if (curn >= 0) {
      float2 o = make_float2(fmaxf(a0, 0.f), fmaxf(a1, 0.f));
      *(float2*)(out + (size_t)(nodeBase + curn) * DIM + 2 * lane) = o;
    }
    // epilogue: zero rows for nodes with no edges
    for (int nn = 0; nn < 32; ++nn) {
      int nl = wave * 32 + nn;
      int node = nodeBase + nl;
      if (cnt[nl] == 0 && node < N) {
        *(float2*)(out + (size_t)node * DIM + 2 * lane) = make_float2(0.f, 0.f);
      }
    }
  } else {
    // Guaranteed-correct fallback (statistically unreachable): per-node scan
    // of all this bucket's segments.
    for (int nn = 0; nn < 32; ++nn) {
      int nl = wave * 32 + nn;
      int node = nodeBase + nl;
      if (node >= N) continue;
      float a0 = 0.f, a1 = 0.f;
      for (int w = 0; w < nsc; ++w) {
        u32 dv = segdir[w];
        int sc = (int)(dv & 0xffffu);
        u32 so = dv >> 16;
        for (int r = 0; r < sc; ++r) {
          u32 lo = bcol[(size_t)w * SC_C + so + r];
          if ((int)(lo >> 25) == nl) {
            u32 d = *(const u32*)(hb + ((lo & 0x01FFFF00u) + lane4));
            float v = bf16_to_f32(bval[(size_t)w * SC_C + so + r]);
            a0 += v * bf16_to_f32(d & 0xffffu);
            a1 += v * bf16_to_f32(d >> 16);
          }
        }
      }
      *(float2*)(out + (size_t)node * DIM + 2 * lane) =
          make_float2(fmaxf(a0, 0.f), fmaxf(a1, 0.f));
    }
  }
}

extern "C" void kernel_launch(void* const* d_in, const int* in_sizes, int n_in,
                              void* d_out, int out_size, void* d_ws, size_t ws_size,
                              hipStream_t stream) {
  const float* x    = (const float*)d_in[0];  // fp32 [N,128]
  const int*   rows = (const int*)d_in[1];    // int32 [E]
  const int*   cols = (const int*)d_in[2];    // int32 [E]
  const float* vals = (const float*)d_in[3];  // fp32 [E]
  const float* W    = (const float*)d_in[4];  // fp32 [128,128]

  const int N = in_sizes[0] / DIM;  // 100000
  const int E = in_sizes[1];        // 3200000
  const int B = (N + AGG_NB - 1) / AGG_NB;  // 782 buckets (128 nodes each)
  const int nsc = (E + SC_C - 1) / SC_C;    // 391 regions

  char* wsb = (char*)d_ws;
  size_t o = 0;
  u16* h = (u16*)wsb;            o += (size_t)N * DIM * sizeof(u16);      // 25.6 MB
  u32* bcol = (u32*)(wsb + o);   o += (size_t)nsc * SC_C * sizeof(u32);   // 12.8 MB
  u16* bval = (u16*)(wsb + o);   o += (size_t)nsc * SC_C * sizeof(u16);   // 6.4 MB
  u32* dirT = (u32*)(wsb + o);   o += (size_t)B * nsc * sizeof(u32);      // 1.2 MB

  gemm_mfma<<<256, 256, 0, stream>>>(x, W, h, N);
  sort_scatter<<<nsc, 256, 0, stream>>>(rows, cols, vals, bcol, bval, dirT, E, B, nsc);
  agg_bucket<<<B, 256, 0, stream>>>(bcol, bval, dirT, (const u32*)h,
                                    (float*)d_out, N, nsc, B);
}

// Round 8
// 345.449 us; speedup vs baseline: 1.1421x; 1.1421x over previous
//
#include <hip/hip_runtime.h>
#include <stdint.h>

typedef unsigned short u16;
typedef unsigned int u32;
typedef unsigned long long u64;
typedef __attribute__((ext_vector_type(8))) short short8;
typedef __attribute__((ext_vector_type(4))) float floatx4;

#define DIM 128
#define DIM2 64     // h dwords per row (2 bf16 per dword)
#define NBK 1792    // scatter scan width >= B = ceil(N/64) = 1563
#define NBK_PT 7    // NBK / 256
#define NB_SH 6     // 64 nodes per bucket
#define AGG_NB 64
#define AGG_CAP 2560  // max staged records/bucket (mean 2048, std 45 -> +11 sigma)
#define SC_C 12800    // edges per scatter region (E/12800 = 250 exactly)
#define NSEG 256      // segment-directory capacity >= nsc = 250

__device__ __forceinline__ u32 f32_to_bf16_rne(float f) {
  u32 u = __float_as_uint(f);
  u32 r = u + 0x7fffu + ((u >> 16) & 1u);
  return r >> 16;
}
__device__ __forceinline__ float bf16_to_f32(u32 u) { return __uint_as_float(u << 16); }
__device__ __forceinline__ u32 pack2bf16(float a, float b) {
  return f32_to_bf16_rne(a) | (f32_to_bf16_rne(b) << 16);
}

union FragU {
  u32 d[4];
  short8 s;
};

// h = x @ W^T via bf16 MFMA. Grid-stride over 64-node tiles with exactly 256
// WGs (1/CU); W staged once per CU.
__global__ __launch_bounds__(256) void gemm_mfma(const float* __restrict__ x,
                                                 const float* __restrict__ W,
                                                 u16* __restrict__ h, int N) {
  __shared__ u32 Wl[DIM * DIM2];  // 32 KB
  int tid = threadIdx.x;
#pragma unroll
  for (int i = 0; i < 8; ++i) {
    int ga = tid + 256 * i;
    int o = ga >> 4, g = ga & 15;
    const float* src = W + (size_t)o * DIM + g * 8;
    floatx4 f0 = *(const floatx4*)src;
    floatx4 f1 = *(const floatx4*)(src + 4);
    int slot = (g + o) & 15;
    u32* dst = &Wl[o * DIM2 + slot * 4];
    dst[0] = pack2bf16(f0.x, f0.y);
    dst[1] = pack2bf16(f0.z, f0.w);
    dst[2] = pack2bf16(f1.x, f1.y);
    dst[3] = pack2bf16(f1.z, f1.w);
  }
  __syncthreads();

  int lane = tid & 63;
  int wave = tid >> 6;
  int m = lane & 15;
  int kg = lane >> 4;
  int ntile = (N + 63) >> 6;  // 64-node tiles

  for (int t = blockIdx.x; t < ntile; t += 256) {
    int nodeBase = t * 64 + wave * 16;
    if (nodeBase >= N) continue;

    short8 a[4];
    const float* xr = x + (size_t)(nodeBase + m) * DIM + kg * 8;
#pragma unroll
    for (int kt = 0; kt < 4; ++kt) {
      floatx4 f0 = *(const floatx4*)(xr + kt * 32);
      floatx4 f1 = *(const floatx4*)(xr + kt * 32 + 4);
      FragU fu;
      fu.d[0] = pack2bf16(f0.x, f0.y);
      fu.d[1] = pack2bf16(f0.z, f0.w);
      fu.d[2] = pack2bf16(f1.x, f1.y);
      fu.d[3] = pack2bf16(f1.z, f1.w);
      a[kt] = fu.s;
    }

#pragma unroll
    for (int ot = 0; ot < 8; ++ot) {
      int o = ot * 16 + m;
      floatx4 acc = {0.f, 0.f, 0.f, 0.f};
#pragma unroll
      for (int kt = 0; kt < 4; ++kt) {
        int slot = (kt * 4 + kg + o) & 15;
        short8 b = *(short8*)&Wl[o * DIM2 + slot * 4];
        acc = __builtin_amdgcn_mfma_f32_16x16x32_bf16(a[kt], b, acc, 0, 0, 0);
      }
#pragma unroll
      for (int r = 0; r < 4; ++r) {
        int node = nodeBase + kg * 4 + r;
        h[(size_t)node * DIM + ot * 16 + m] = (u16)f32_to_bf16_rne(acc[r]);
      }
    }
  }
}

// Exclusive scan over NBK=1792 LDS counters, 7 contiguous per thread.
__device__ __forceinline__ void scan_nbk(u32* cnt, u32* excl, u32* wtot) {
  int tid = threadIdx.x, lane = tid & 63, wave = tid >> 6;
  u32 c[NBK_PT], sum = 0;
#pragma unroll
  for (int k = 0; k < NBK_PT; ++k) {
    c[k] = cnt[tid * NBK_PT + k];
    sum += c[k];
  }
  u32 inc = sum;
#pragma unroll
  for (int d = 1; d < 64; d <<= 1) {
    u32 t = __shfl_up(inc, d, 64);
    if (lane >= d) inc += t;
  }
  if (lane == 63) wtot[wave] = inc;
  __syncthreads();
  u32 wbase = 0;
  for (int w = 0; w < wave; ++w) wbase += wtot[w];
  u32 run = wbase + inc - sum;
#pragma unroll
  for (int k = 0; k < NBK_PT; ++k) {
    excl[tid * NBK_PT + k] = run;
    run += c[k];
  }
  __syncthreads();
}

// Region-local sort-scatter (no global atomics). Each WG bucket-sorts its
// 12800-edge chunk in LDS (segments avg 8.2 records, up from R6's 5.2),
// streams it to its OWN region (coalesced), and writes the TRANSPOSED
// directory dirT[b][wg] = (start<<16)|cnt. LDS ~89 KB -> 1 WG/CU; 250 WGs.
__global__ __launch_bounds__(256) void sort_scatter(const int* __restrict__ rows,
                                                    const int* __restrict__ cols,
                                                    const float* __restrict__ vals,
                                                    u32* __restrict__ bcol,
                                                    u16* __restrict__ bval,
                                                    u32* __restrict__ dirT, int E, int B,
                                                    int nsc) {
  __shared__ u32 hist[NBK];    // counts -> running ptr
  __shared__ u32 starts[NBK];  // exclusive scan
  __shared__ u32 wtot[4];
  __shared__ u32 s_lo[SC_C];   // 50 KB
  __shared__ u16 s_val[SC_C];  // 25 KB
  int tid = threadIdx.x;
  int wg = blockIdx.x;
  int base = wg * SC_C;
  int tot = min(SC_C, E - base);

  for (int b = tid; b < NBK; b += 256) hist[b] = 0;
  __syncthreads();
  // pass 1: local bucket histogram
  for (int j = tid; j < tot; j += 256) {
    atomicAdd(&hist[((u32)rows[base + j]) >> NB_SH], 1u);
  }
  __syncthreads();
  scan_nbk(hist, starts, wtot);
  for (int b = tid; b < NBK; b += 256) hist[b] = starts[b];  // running ptrs
  __syncthreads();
  // pass 2: rank final records into bucket-grouped LDS (all reads coalesced)
  for (int j = tid; j < tot; j += 256) {
    u32 r = (u32)rows[base + j];
    u32 bk = r >> NB_SH;
    u32 p = atomicAdd(&hist[bk], 1u);
    s_lo[p] = ((r & 63u) << 26) | ((u32)cols[base + j] << 8);
    s_val[p] = (u16)f32_to_bf16_rne(vals[base + j]);
  }
  __syncthreads();
  // flush: pure streaming writes to own region
  for (int i = tid; i < tot; i += 256) {
    bcol[(size_t)base + i] = s_lo[i];
    bval[(size_t)base + i] = s_val[i];
  }
  // transposed directory (strided u32 writes, 1.56 MB total, L2-merged)
  for (int b = tid; b < B; b += 256) {
    dirT[(size_t)b * nsc + wg] = (starts[b] << 16) | (hist[b] - starts[b]);
  }
}

// One WG per 64-node bucket. Coalesced dirT row; segment scan (250 entries,
// single wave); LDS map[g]->segment replaces R6's per-record 9-step binary
// search; then node counting-sort + flat walk with depth-8 gather pipeline +
// direct relu'd global flush (R5's verified pass C).
__global__ __launch_bounds__(256) void agg_bucket(const u32* __restrict__ bcol,
                                                  const u16* __restrict__ bval,
                                                  const u32* __restrict__ dirT,
                                                  const u32* __restrict__ h,
                                                  float* __restrict__ out, int N,
                                                  int nsc, int B) {
  __shared__ u64 s_rec[AGG_CAP];  // 20 KB
  __shared__ u16 map[AGG_CAP];    // 5 KB
  __shared__ u32 segdir[NSEG], segdst[NSEG];
  __shared__ u32 cnt[AGG_NB], excl[AGG_NB], ptr[AGG_NB];
  __shared__ u32 sT;
  int tid = threadIdx.x, lane = tid & 63, wave = tid >> 6;
  int b = blockIdx.x;
  int nodeBase = b << NB_SH;
  int lane4 = lane * 4;
  const char* hb = (const char*)h;

  // coalesced directory row + zero node counters
  for (int w = tid; w < NSEG; w += 256)
    segdir[w] = (w < nsc) ? dirT[(size_t)b * nsc + w] : 0u;
  if (tid < AGG_NB) cnt[tid] = 0;
  __syncthreads();
  // exclusive scan of 256 segment counts with one wave (4 per lane)
  if (tid < 64) {
    u32 c[4], sum = 0;
#pragma unroll
    for (int k = 0; k < 4; ++k) {
      c[k] = segdir[lane * 4 + k] & 0xffffu;
      sum += c[k];
    }
    u32 inc = sum;
#pragma unroll
    for (int d = 1; d < 64; d <<= 1) {
      u32 t = __shfl_up(inc, d, 64);
      if (lane >= d) inc += t;
    }
    u32 run = inc - sum;
#pragma unroll
    for (int k = 0; k < 4; ++k) {
      segdst[lane * 4 + k] = run;
      run += c[k];
    }
    if (lane == 63) sT = inc;
  }
  __syncthreads();
  int T = (int)sT;

  if (T <= AGG_CAP) {
    // build record->segment map (total T u16 writes across the WG)
    for (int w = tid; w < nsc; w += 256) {
      u32 dv = segdir[w];
      u32 c = dv & 0xffffu;
      u32 d0 = segdst[w];
      for (u32 i = 0; i < c; ++i) map[d0 + i] = (u16)w;
    }
    __syncthreads();
    // pass A: stage records via map + node histogram
    u32 rlo[10], rv[10];
#pragma unroll
    for (int k = 0; k < 10; ++k) {
      int g = tid + 256 * k;
      rlo[k] = 0;
      rv[k] = 0;
      if (g < T) {
        int w = map[g];
        u32 dv = segdir[w];
        u32 src = (u32)w * SC_C + (dv >> 16) + ((u32)g - segdst[w]);
        rlo[k] = bcol[src];
        rv[k] = bval[src];
        atomicAdd(&cnt[rlo[k] >> 26], 1u);
      }
    }
    __syncthreads();
    // scan 64 node counters (wave 0)
    if (tid < 64) {
      u32 c = cnt[tid], inc = c;
#pragma unroll
      for (int d = 1; d < 64; d <<= 1) {
        u32 t = __shfl_up(inc, d, 64);
        if (lane >= d) inc += t;
      }
      excl[tid] = inc - c;
      ptr[tid] = inc - c;
    }
    __syncthreads();
    // pass B: rank into node-sorted LDS staging (u64 records)
#pragma unroll
    for (int k = 0; k < 10; ++k) {
      int g = tid + 256 * k;
      if (g < T) {
        u32 p = atomicAdd(&ptr[rlo[k] >> 26], 1u);
        s_rec[p] = ((u64)(rv[k] << 16) << 32) | rlo[k];
      }
    }
    __syncthreads();
    // pass C: flat walk of my wave's 16 nodes' contiguous segment
    int wbeg = (int)excl[wave * 16];
    int wend = (int)ptr[wave * 16 + 15];
    float a0 = 0.f, a1 = 0.f;
    int curn = -1;
    for (int e = wbeg; e < wend; e += 8) {
      u32 lo8[8];
      float v8[8];
      u32 hd[8];
#pragma unroll
      for (int g = 0; g < 8; ++g) {
        int ee = e + g;
        bool act = ee < wend;
        u64 r = s_rec[act ? ee : (wend - 1)];  // wave-uniform broadcast read
        lo8[g] = (u32)r;
        v8[g] = act ? __uint_as_float((u32)(r >> 32)) : 0.f;
      }
#pragma unroll
      for (int g = 0; g < 8; ++g) {
        hd[g] = *(const u32*)(hb + ((lo8[g] & 0x01FFFF00u) + lane4));
      }
#pragma unroll
      for (int g = 0; g < 8; ++g) {
        int nid = __builtin_amdgcn_readfirstlane((int)(lo8[g] >> 26));
        if (nid != curn) {  // scalar branch, once per run
          if (curn >= 0) {
            float2 o = make_float2(fmaxf(a0, 0.f), fmaxf(a1, 0.f));
            *(float2*)(out + (size_t)(nodeBase + curn) * DIM + 2 * lane) = o;
          }
          curn = nid;
          a0 = 0.f;
          a1 = 0.f;
        }
        float v = v8[g];
        a0 += v * bf16_to_f32(hd[g] & 0xffffu);
        a1 += v * bf16_to_f32(hd[g] >> 16);
      }
    }
    if (curn >= 0) {
      float2 o = make_float2(fmaxf(a0, 0.f), fmaxf(a1, 0.f));
      *(float2*)(out + (size_t)(nodeBase + curn) * DIM + 2 * lane) = o;
    }
    // epilogue: zero rows for nodes with no edges
    for (int nn = 0; nn < 16; ++nn) {
      int nl = wave * 16 + nn;
      int node = nodeBase + nl;
      if (cnt[nl] == 0 && node < N) {
        *(float2*)(out + (size_t)node * DIM + 2 * lane) = make_float2(0.f, 0.f);
      }
    }
  } else {
    // Guaranteed-correct fallback (statistically unreachable): per-node scan
    // of all this bucket's segments.
    for (int nn = 0; nn < 16; ++nn) {
      int nl = wave * 16 + nn;
      int node = nodeBase + nl;
      if (node >= N) continue;
      float a0 = 0.f, a1 = 0.f;
      for (int w = 0; w < nsc; ++w) {
        u32 dv = segdir[w];
        int sc = (int)(dv & 0xffffu);
        u32 so = dv >> 16;
        for (int r = 0; r < sc; ++r) {
          u32 lo = bcol[(size_t)w * SC_C + so + r];
          if ((int)(lo >> 26) == nl) {
            u32 d = *(const u32*)(hb + ((lo & 0x01FFFF00u) + lane4));
            float v = bf16_to_f32(bval[(size_t)w * SC_C + so + r]);
            a0 += v * bf16_to_f32(d & 0xffffu);
            a1 += v * bf16_to_f32(d >> 16);
          }
        }
      }
      *(float2*)(out + (size_t)node * DIM + 2 * lane) =
          make_float2(fmaxf(a0, 0.f), fmaxf(a1, 0.f));
    }
  }
}

extern "C" void kernel_launch(void* const* d_in, const int* in_sizes, int n_in,
                              void* d_out, int out_size, void* d_ws, size_t ws_size,
                              hipStream_t stream) {
  const float* x    = (const float*)d_in[0];  // fp32 [N,128]
  const int*   rows = (const int*)d_in[1];    // int32 [E]
  const int*   cols = (const int*)d_in[2];    // int32 [E]
  const float* vals = (const float*)d_in[3];  // fp32 [E]
  const float* W    = (const float*)d_in[4];  // fp32 [128,128]

  const int N = in_sizes[0] / DIM;  // 100000
  const int E = in_sizes[1];        // 3200000
  const int B = (N + AGG_NB - 1) / AGG_NB;  // 1563 buckets (64 nodes each)
  const int nsc = (E + SC_C - 1) / SC_C;    // 250 regions

  char* wsb = (char*)d_ws;
  size_t o = 0;
  u16* h = (u16*)wsb;            o += (size_t)N * DIM * sizeof(u16);      // 25.6 MB
  u32* bcol = (u32*)(wsb + o);   o += (size_t)nsc * SC_C * sizeof(u32);   // 12.8 MB
  u16* bval = (u16*)(wsb + o);   o += (size_t)nsc * SC_C * sizeof(u16);   // 6.4 MB
  u32* dirT = (u32*)(wsb + o);   o += (size_t)B * nsc * sizeof(u32);      // 1.56 MB

  gemm_mfma<<<256, 256, 0, stream>>>(x, W, h, N);
  sort_scatter<<<nsc, 256, 0, stream>>>(rows, cols, vals, bcol, bval, dirT, E, B, nsc);
  agg_bucket<<<B, 256, 0, stream>>>(bcol, bval, dirT, (const u32*)h,
                                    (float*)d_out, N, nsc, B);
}